// Round 15
// baseline (306.215 us; speedup 1.0000x reference)
//
#include <hip/hip_runtime.h>
#include <hip/hip_bf16.h>

#define NNODES 50000
#define NEDGES 800000
#define FIN    128
#define HID    64
#define HEADS  4
#define NGRAPH 256
#define NCLS   10
#define DTOT   256   // HEADS*HID
#define ALPHA  0.01f
#define CAPLG  6          // 64 slots/node bin; Poisson(16) => P(deg>64) ~ 1e-20
#define CAP    (1 << CAPLG)

typedef short bf16x8 __attribute__((ext_vector_type(8)));
typedef float f32x4  __attribute__((ext_vector_type(4)));

#define GG     ((NNODES + 127) / 128)       // 391 gemm blocks
#define ECH    ((NEDGES + 2047) / 2048)     // 391 edge chunks (2048 edges each)
#define W1BF   (FIN * DTOT / 512)           // 64 w1t blocks (512 thr)
#define NBF    ((NNODES + 511) / 512)       // 98 gstart blocks
#define W2BF   (DTOT * DTOT / 512)          // 128 W2-transpose blocks

__device__ __forceinline__ ushort f2bf(float v) {
    return __bfloat16_as_ushort(__float2bfloat16(v));
}
__device__ __forceinline__ float blo(unsigned u) { return __uint_as_float(u << 16); }
__device__ __forceinline__ float bhi(unsigned u) { return __uint_as_float(u & 0xffff0000u); }
__device__ __forceinline__ unsigned pack2(float lo, float hi) {
    return ((unsigned)f2bf(hi) << 16) | (unsigned)f2bf(lo);
}
__device__ __forceinline__ bf16x8 cvt8v(f32x4 lo, f32x4 hi) {
    bf16x8 r;
    r[0] = (short)f2bf(lo[0]); r[1] = (short)f2bf(lo[1]);
    r[2] = (short)f2bf(lo[2]); r[3] = (short)f2bf(lo[3]);
    r[4] = (short)f2bf(hi[0]); r[5] = (short)f2bf(hi[1]);
    r[6] = (short)f2bf(hi[2]); r[7] = (short)f2bf(hi[3]);
    return r;
}

// ---------------- XCD-partitioned edge binning + W1 transpose (fused; saves a launch) ----------------
// Partition p(d)=(d>>4)&7 keeps each 64B cursor/bin line on one XCD (R13-proven).
// NEW (R15): edge-array loads are NON-TEMPORAL — each partition streams ~4.8MB of
// read-once src/dst through a 4MB L2 while needing its 0.8MB bins resident; nt keeps
// the streaming reads from evicting bin lines (self-pollution was the residual cost).
__global__ __launch_bounds__(512) void k_bin(const int* __restrict__ src,
                                             const int* __restrict__ dst,
                                             int* __restrict__ cursor,
                                             ushort* __restrict__ esrc,
                                             const float* __restrict__ W1,
                                             ushort* __restrict__ W1t) {
    if (blockIdx.x >= ECH * 8) {
        int id = (blockIdx.x - ECH * 8) * 512 + threadIdx.x;   // < 32768
        int n = id & 255, k = id >> 8;                          // k < 128
        W1t[n * FIN + (((k >> 3) ^ (n & 7)) << 3) + (k & 7)] = f2bf(W1[k * DTOT + n]);
        return;
    }
    const int p = blockIdx.x & 7;
    const int c = blockIdx.x >> 3;
    int ebase = c * 2048 + threadIdx.x;
#pragma unroll
    for (int k = 0; k < 4; ++k) {
        int e = ebase + k * 512;
        if (e < NEDGES) {
            int d = __builtin_nontemporal_load(dst + e);
            if (((d >> 4) & 7) == p) {
                int s = __builtin_nontemporal_load(src + e);
                int pos = atomicAdd(&cursor[d], 1);
                if (pos < CAP) esrc[(d << CAPLG) + pos] = (ushort)s;
            }
        }
    }
}

// ---------------- fused: gemm1 (A=f32 x, nt loads) + gstart + W2 transpose ----------------
// x is a 25.6MB read-once stream: nt loads keep the 64KB W1t B-panel L2-hot across
// the 391 blocks' re-staging.
__global__ __launch_bounds__(512) void k_gemm1_fused(const float* __restrict__ x,
                                                     const ushort* __restrict__ W1t,
                                                     ushort* __restrict__ Cbf,
                                                     float* __restrict__ ls,
                                                     float* __restrict__ ld_,
                                                     const float* __restrict__ a_src,
                                                     const float* __restrict__ a_dst,
                                                     const int* __restrict__ batch,
                                                     int* __restrict__ gstart,
                                                     const float* __restrict__ W2,
                                                     ushort* __restrict__ W2t) {
    __shared__ ushort Bl[256 * 64];   // 32 KB
    const int b = blockIdx.x;
    const int tid = threadIdx.x;
    if (b >= GG) {
        const int r = b - GG;
        if (r < NBF) {
            int i = r * 512 + tid;
            if (i < NNODES) {
                int bb = batch[i];
                if (i == 0) {
                    for (int g = 0; g <= bb; ++g) gstart[g] = 0;
                } else {
                    int pb = batch[i - 1];
                    if (pb != bb) for (int g = pb + 1; g <= bb; ++g) gstart[g] = i;
                }
                if (i == NNODES - 1)
                    for (int g = bb + 1; g <= NGRAPH; ++g) gstart[g] = NNODES;
            }
        } else {
            int id = (r - NBF) * 512 + tid;   // < 65536
            int n = id & 255, k = id >> 8;
            W2t[n * DTOT + (((k >> 3) ^ (n & 7)) << 3) + (k & 7)] = f2bf(W2[k * DTOT + n]);
        }
        return;
    }

    // ---- gemm part: R7-proven structure, K=FIN, A=f32 inline cast ----
    constexpr int K = FIN;
    const int w    = tid >> 6;
    const int lane = tid & 63;
    const int l15  = lane & 15;
    const int quad = lane >> 4;
    const int m0 = b * 128;

    f32x4 acc[16];
#pragma unroll
    for (int nf = 0; nf < 16; ++nf) acc[nf] = (f32x4){0.f, 0.f, 0.f, 0.f};

    int rowA0 = m0 + w * 16 + l15;  if (rowA0 >= NNODES) rowA0 = NNODES - 1;
    const float* pa0f = x + (size_t)rowA0 * K + quad * 8;

#pragma unroll
    for (int kc = 0; kc < K / 64; ++kc) {
        {
#pragma unroll
            for (int idx = tid; idx < 2048; idx += 512) {
                int n = idx >> 3, c8 = (idx ^ n) & 7;
                *(uint4*)&Bl[n * 64 + c8 * 8] =
                    *(const uint4*)&W1t[(size_t)n * K + kc * 64 + c8 * 8];
            }
        }
        __syncthreads();
#pragma unroll
        for (int ks = 0; ks < 2; ++ks) {
            const float* p = pa0f + kc * 64 + ks * 32;
            f32x4 alo = __builtin_nontemporal_load((const f32x4*)p);
            f32x4 ahi = __builtin_nontemporal_load((const f32x4*)(p + 4));
            bf16x8 a0 = cvt8v(alo, ahi);
#pragma unroll
            for (int nh = 0; nh < 4; ++nh) {
                bf16x8 bfr[4];
#pragma unroll
                for (int j = 0; j < 4; ++j) {
                    int n = (nh * 4 + j) * 16 + l15;
                    int c = (ks * 4 + quad) ^ (n & 7);
                    bfr[j] = *(const bf16x8*)&Bl[n * 64 + (c << 3)];
                }
#pragma unroll
                for (int j = 0; j < 4; ++j)
                    acc[nh * 4 + j] = __builtin_amdgcn_mfma_f32_16x16x32_bf16(a0, bfr[j], acc[nh * 4 + j], 0, 0, 0);
            }
        }
        __syncthreads();
    }

    float as[16], ad[16];
#pragma unroll
    for (int nf = 0; nf < 16; ++nf) {
        int head = nf >> 2;
        as[nf] = a_src[head * HID + (nf & 3) * 16 + l15];
        ad[nf] = a_dst[head * HID + (nf & 3) * 16 + l15];
    }
#pragma unroll
    for (int reg = 0; reg < 4; ++reg) {
        int row = m0 + w * 16 + quad * 4 + reg;
        bool ok = row < NNODES;
        if (ok) {
#pragma unroll
            for (int nf = 0; nf < 16; ++nf)
                Cbf[(size_t)row * DTOT + nf * 16 + l15] = f2bf(acc[nf][reg]);
        }
        float sh[4], dh[4];
#pragma unroll
        for (int head = 0; head < 4; ++head) {
            float s = 0.f, d = 0.f;
#pragma unroll
            for (int j = 0; j < 4; ++j) {
                int nf = head * 4 + j;
                s += acc[nf][reg] * as[nf];
                d += acc[nf][reg] * ad[nf];
            }
            sh[head] = s; dh[head] = d;
        }
#pragma unroll
        for (int off = 1; off < 16; off <<= 1) {
#pragma unroll
            for (int head = 0; head < 4; ++head) {
                sh[head] += __shfl_xor(sh[head], off);
                dh[head] += __shfl_xor(dh[head], off);
            }
        }
        if (ok && l15 == 0) {
#pragma unroll
            for (int head = 0; head < 4; ++head) {
                ls[row * HEADS + head]  = sh[head];
                ld_[row * HEADS + head] = dh[head];
            }
        }
    }
}

// ---------------- MFMA GEMM (layer 2): Cbf[M,256] = A[M,256] @ W2[256,256] ----------------
__global__ __launch_bounds__(512) void k_gemm_mfma2(const ushort* __restrict__ Abf,
                                                    const ushort* __restrict__ Bt,
                                                    ushort* __restrict__ Cbf,
                                                    float* __restrict__ ls,
                                                    float* __restrict__ ld_,
                                                    const float* __restrict__ a_src,
                                                    const float* __restrict__ a_dst,
                                                    int M) {
    constexpr int K = DTOT;
    __shared__ ushort Bl[256 * 64];   // 32 KB
    const int tid  = threadIdx.x;
    const int w    = tid >> 6;
    const int lane = tid & 63;
    const int l15  = lane & 15;
    const int quad = lane >> 4;
    const int m0 = blockIdx.x * 128;

    f32x4 acc[16];
#pragma unroll
    for (int nf = 0; nf < 16; ++nf) acc[nf] = (f32x4){0.f, 0.f, 0.f, 0.f};

    int rowA0 = m0 + w * 16 + l15;  if (rowA0 >= M) rowA0 = M - 1;
    const ushort* pa0b = Abf + (size_t)rowA0 * K + quad * 8;

#pragma unroll
    for (int kc = 0; kc < K / 64; ++kc) {
        {
#pragma unroll
            for (int idx = tid; idx < 2048; idx += 512) {
                int n = idx >> 3, c8 = (idx ^ n) & 7;
                *(uint4*)&Bl[n * 64 + c8 * 8] =
                    *(const uint4*)&Bt[(size_t)n * K + kc * 64 + c8 * 8];
            }
        }
        __syncthreads();
#pragma unroll
        for (int ks = 0; ks < 2; ++ks) {
            bf16x8 a0 = *(const bf16x8*)(pa0b + kc * 64 + ks * 32);
#pragma unroll
            for (int nh = 0; nh < 4; ++nh) {
                bf16x8 bfr[4];
#pragma unroll
                for (int j = 0; j < 4; ++j) {
                    int n = (nh * 4 + j) * 16 + l15;
                    int c = (ks * 4 + quad) ^ (n & 7);
                    bfr[j] = *(const bf16x8*)&Bl[n * 64 + (c << 3)];
                }
#pragma unroll
                for (int j = 0; j < 4; ++j)
                    acc[nh * 4 + j] = __builtin_amdgcn_mfma_f32_16x16x32_bf16(a0, bfr[j], acc[nh * 4 + j], 0, 0, 0);
            }
        }
        __syncthreads();
    }

    float as[16], ad[16];
#pragma unroll
    for (int nf = 0; nf < 16; ++nf) {
        int head = nf >> 2;
        as[nf] = a_src[head * HID + (nf & 3) * 16 + l15];
        ad[nf] = a_dst[head * HID + (nf & 3) * 16 + l15];
    }
#pragma unroll
    for (int reg = 0; reg < 4; ++reg) {
        int row = m0 + w * 16 + quad * 4 + reg;
        bool ok = row < M;
        if (ok) {
#pragma unroll
            for (int nf = 0; nf < 16; ++nf)
                Cbf[(size_t)row * DTOT + nf * 16 + l15] = f2bf(acc[nf][reg]);
        }
        float sh[4], dh[4];
#pragma unroll
        for (int head = 0; head < 4; ++head) {
            float s = 0.f, d = 0.f;
#pragma unroll
            for (int j = 0; j < 4; ++j) {
                int nf = head * 4 + j;
                s += acc[nf][reg] * as[nf];
                d += acc[nf][reg] * ad[nf];
            }
            sh[head] = s; dh[head] = d;
        }
#pragma unroll
        for (int off = 1; off < 16; off <<= 1) {
#pragma unroll
            for (int head = 0; head < 4; ++head) {
                sh[head] += __shfl_xor(sh[head], off);
                dh[head] += __shfl_xor(dh[head], off);
            }
        }
        if (ok && l15 == 0) {
#pragma unroll
            for (int head = 0; head < 4; ++head) {
                ls[row * HEADS + head]  = sh[head];
                ld_[row * HEADS + head] = dh[head];
            }
        }
    }
}

// ---------------- fused softmax + gather-aggregate + ELU (R7-exact: at its memory wall) ----------------
__global__ __launch_bounds__(256) void k_gat_aggr(const int* __restrict__ cnt,
                                                  const ushort* __restrict__ esrc,
                                                  const ushort* __restrict__ Whbf,
                                                  const float* __restrict__ ls,
                                                  const float* __restrict__ ld_,
                                                  ushort* __restrict__ out) {
    const int wv   = threadIdx.x >> 6;
    const int lane = threadIdx.x & 63;
    const int i    = blockIdx.x * 4 + wv;
    if (i >= NNODES) return;
    const int half = lane >> 5;
    const int l32  = lane & 31;
    const int h    = l32 >> 3;
    const int e0 = i << CAPLG;
    int deg = cnt[i]; if (deg > CAP) deg = CAP;
    const int e1 = e0 + deg;
    const float ldv = ld_[i * HEADS + h];

    float ac[8] = {};
    float z = 0.f;
    const int ch = 8 * l32;
    int e = e0 + half;
    for (; e + 6 < e1; e += 8) {
        int s0 = (int)esrc[e], s1 = (int)esrc[e + 2], s2 = (int)esrc[e + 4], s3 = (int)esrc[e + 6];
        float l0 = ls[s0 * HEADS + h] + ldv;
        float l1 = ls[s1 * HEADS + h] + ldv;
        float l2 = ls[s2 * HEADS + h] + ldv;
        float l3 = ls[s3 * HEADS + h] + ldv;
        uint4 u0 = *(const uint4*)&Whbf[(size_t)s0 * DTOT + ch];
        uint4 u1 = *(const uint4*)&Whbf[(size_t)s1 * DTOT + ch];
        uint4 u2 = *(const uint4*)&Whbf[(size_t)s2 * DTOT + ch];
        uint4 u3 = *(const uint4*)&Whbf[(size_t)s3 * DTOT + ch];
        float p0 = __expf(l0 > 0.f ? l0 : ALPHA * l0);
        float p1 = __expf(l1 > 0.f ? l1 : ALPHA * l1);
        float p2 = __expf(l2 > 0.f ? l2 : ALPHA * l2);
        float p3 = __expf(l3 > 0.f ? l3 : ALPHA * l3);
        z += p0 + p1 + p2 + p3;
        ac[0] = fmaf(p0, blo(u0.x), ac[0]); ac[1] = fmaf(p0, bhi(u0.x), ac[1]);
        ac[2] = fmaf(p0, blo(u0.y), ac[2]); ac[3] = fmaf(p0, bhi(u0.y), ac[3]);
        ac[4] = fmaf(p0, blo(u0.z), ac[4]); ac[5] = fmaf(p0, bhi(u0.z), ac[5]);
        ac[6] = fmaf(p0, blo(u0.w), ac[6]); ac[7] = fmaf(p0, bhi(u0.w), ac[7]);
        ac[0] = fmaf(p1, blo(u1.x), ac[0]); ac[1] = fmaf(p1, bhi(u1.x), ac[1]);
        ac[2] = fmaf(p1, blo(u1.y), ac[2]); ac[3] = fmaf(p1, bhi(u1.y), ac[3]);
        ac[4] = fmaf(p1, blo(u1.z), ac[4]); ac[5] = fmaf(p1, bhi(u1.z), ac[5]);
        ac[6] = fmaf(p1, blo(u1.w), ac[6]); ac[7] = fmaf(p1, bhi(u1.w), ac[7]);
        ac[0] = fmaf(p2, blo(u2.x), ac[0]); ac[1] = fmaf(p2, bhi(u2.x), ac[1]);
        ac[2] = fmaf(p2, blo(u2.y), ac[2]); ac[3] = fmaf(p2, bhi(u2.y), ac[3]);
        ac[4] = fmaf(p2, blo(u2.z), ac[4]); ac[5] = fmaf(p2, bhi(u2.z), ac[5]);
        ac[6] = fmaf(p2, blo(u2.w), ac[6]); ac[7] = fmaf(p2, bhi(u2.w), ac[7]);
        ac[0] = fmaf(p3, blo(u3.x), ac[0]); ac[1] = fmaf(p3, bhi(u3.x), ac[1]);
        ac[2] = fmaf(p3, blo(u3.y), ac[2]); ac[3] = fmaf(p3, bhi(u3.y), ac[3]);
        ac[4] = fmaf(p3, blo(u3.z), ac[4]); ac[5] = fmaf(p3, bhi(u3.z), ac[5]);
        ac[6] = fmaf(p3, blo(u3.w), ac[6]); ac[7] = fmaf(p3, bhi(u3.w), ac[7]);
    }
    for (; e < e1; e += 2) {
        int s0 = (int)esrc[e];
        float l0 = ls[s0 * HEADS + h] + ldv;
        uint4 u0 = *(const uint4*)&Whbf[(size_t)s0 * DTOT + ch];
        float p0 = __expf(l0 > 0.f ? l0 : ALPHA * l0);
        z += p0;
        ac[0] = fmaf(p0, blo(u0.x), ac[0]); ac[1] = fmaf(p0, bhi(u0.x), ac[1]);
        ac[2] = fmaf(p0, blo(u0.y), ac[2]); ac[3] = fmaf(p0, bhi(u0.y), ac[3]);
        ac[4] = fmaf(p0, blo(u0.z), ac[4]); ac[5] = fmaf(p0, bhi(u0.z), ac[5]);
        ac[6] = fmaf(p0, blo(u0.w), ac[6]); ac[7] = fmaf(p0, bhi(u0.w), ac[7]);
    }

#pragma unroll
    for (int j = 0; j < 8; ++j) ac[j] += __shfl_xor(ac[j], 32);
    z += __shfl_xor(z, 32);

    if (half == 0) {
        const float inv = 1.f / (z + 1e-16f);
        float v[8];
#pragma unroll
        for (int j = 0; j < 8; ++j) {
            float t = ac[j] * inv;
            v[j] = t > 0.f ? t : __expf(t) - 1.f;
        }
        uint4 pk;
        pk.x = pack2(v[0], v[1]);
        pk.y = pack2(v[2], v[3]);
        pk.z = pack2(v[4], v[5]);
        pk.w = pack2(v[6], v[7]);
        *(uint4*)(out + (size_t)i * DTOT + ch) = pk;
    }
}

// ---------------- fused pooling + final linear (vectorized; 34KB LDS) ----------------
__global__ __launch_bounds__(1024) void k_pool_final(const ushort* __restrict__ h2bf,
                                                     const int* __restrict__ gstart,
                                                     const float* __restrict__ W,
                                                     const float* __restrict__ b,
                                                     float* __restrict__ out) {
    __shared__ float smx[16][256];   // 16 KB
    __shared__ float ssm[16][256];   // 16 KB
    __shared__ float pooled[2 * DTOT];
    int g = blockIdx.x, t = threadIdx.x;
    int cg = t & 31, j = t >> 5;          // 32 node-strides, 8 channels/thread
    int s = gstart[g], e = gstart[g + 1];
    float mx[8], sm[8];
#pragma unroll
    for (int k = 0; k < 8; ++k) { mx[k] = -INFINITY; sm[k] = 0.f; }
    for (int n = s + j; n < e; n += 32) {
        uint4 u = *(const uint4*)&h2bf[(size_t)n * DTOT + cg * 8];
        float v0 = blo(u.x), v1 = bhi(u.x), v2 = blo(u.y), v3 = bhi(u.y);
        float v4 = blo(u.z), v5 = bhi(u.z), v6 = blo(u.w), v7 = bhi(u.w);
        mx[0] = fmaxf(mx[0], v0); sm[0] += v0;
        mx[1] = fmaxf(mx[1], v1); sm[1] += v1;
        mx[2] = fmaxf(mx[2], v2); sm[2] += v2;
        mx[3] = fmaxf(mx[3], v3); sm[3] += v3;
        mx[4] = fmaxf(mx[4], v4); sm[4] += v4;
        mx[5] = fmaxf(mx[5], v5); sm[5] += v5;
        mx[6] = fmaxf(mx[6], v6); sm[6] += v6;
        mx[7] = fmaxf(mx[7], v7); sm[7] += v7;
    }
#pragma unroll
    for (int k = 0; k < 8; ++k) {
        mx[k] = fmaxf(mx[k], __shfl_xor(mx[k], 32));
        sm[k] += __shfl_xor(sm[k], 32);
    }
    int wave = t >> 6, lane = t & 63;
    if (lane < 32) {
        *(float4*)&smx[wave][lane * 8]     = make_float4(mx[0], mx[1], mx[2], mx[3]);
        *(float4*)&smx[wave][lane * 8 + 4] = make_float4(mx[4], mx[5], mx[6], mx[7]);
        *(float4*)&ssm[wave][lane * 8]     = make_float4(sm[0], sm[1], sm[2], sm[3]);
        *(float4*)&ssm[wave][lane * 8 + 4] = make_float4(sm[4], sm[5], sm[6], sm[7]);
    }
    __syncthreads();
    if (t < 256) {
        float m = -INFINITY, su = 0.f;
#pragma unroll
        for (int jj = 0; jj < 16; ++jj) {
            m = fmaxf(m, smx[jj][t]);
            su += ssm[jj][t];
        }
        int cnt = e - s;
        if (cnt <= 0) m = 0.f;
        pooled[t] = m;
        pooled[DTOT + t] = su / (float)(cnt > 0 ? cnt : 1);
    }
    __syncthreads();
    int wv = t >> 6;
    if (wv < NCLS) {
        float acc = 0.f;
        for (int k = lane; k < 2 * DTOT; k += 64)
            acc += pooled[k] * W[k * NCLS + wv];
#pragma unroll
        for (int off = 32; off; off >>= 1) acc += __shfl_down(acc, off);
        if (lane == 0)
            out[g * NCLS + wv] = acc + b[wv];
    }
}

extern "C" void kernel_launch(void* const* d_in, const int* in_sizes, int n_in,
                              void* d_out, int out_size, void* d_ws, size_t ws_size,
                              hipStream_t stream) {
    const float* x     = (const float*)d_in[0];
    const int*   ei    = (const int*)d_in[1];
    const int*   batch = (const int*)d_in[2];
    const float* W1    = (const float*)d_in[3];
    const float* a1s   = (const float*)d_in[4];
    const float* a1d   = (const float*)d_in[5];
    const float* W2    = (const float*)d_in[6];
    const float* a2s   = (const float*)d_in[7];
    const float* a2d   = (const float*)d_in[8];
    const float* linW  = (const float*)d_in[9];
    const float* linb  = (const float*)d_in[10];
    float* out = (float*)d_out;

    const int* src = ei;
    const int* dst = ei + NEDGES;

    size_t off = 0;
    char* base = (char*)d_ws;
    auto alloc = [&](size_t bytes) -> void* {
        void* p = base + off;
        off += (bytes + 255) & ~(size_t)255;
        return p;
    };
    ushort* Whbf   = (ushort*)alloc((size_t)NNODES * DTOT * 2);
    ushort* h1bf   = (ushort*)alloc((size_t)NNODES * DTOT * 2);
    ushort* h2bf   = (ushort*)alloc((size_t)NNODES * DTOT * 2);
    float*  ls     = (float*)alloc((size_t)NNODES * HEADS * 4);
    float*  ld_    = (float*)alloc((size_t)NNODES * HEADS * 4);
    int*    cursor = (int*)alloc((size_t)NNODES * 4);
    ushort* esrc   = (ushort*)alloc((size_t)(NNODES << CAPLG) * 2);  // 6.4 MB bins
    int*    gstart = (int*)alloc((size_t)(NGRAPH + 1) * 4);
    ushort* W1t    = (ushort*)alloc((size_t)DTOT * FIN * 2);
    ushort* W2t    = (ushort*)alloc((size_t)DTOT * DTOT * 2);

    hipMemsetAsync(cursor, 0, (size_t)NNODES * 4, stream);

    // Partitioned binning (nt edge reads; L2-resident bins per XCD) + W1 transpose tail
    k_bin<<<ECH * 8 + W1BF, 512, 0, stream>>>(src, dst, cursor, esrc, W1, W1t);

    // Layer 1 GEMM (nt x loads) fused with gstart | W2 transpose (tiny tails)
    int fgrid = GG + NBF + W2BF;   // 391 + 98 + 128 = 617
    k_gemm1_fused<<<fgrid, 512, 0, stream>>>(x, W1t, Whbf, ls, ld_, a1s, a1d,
                                             batch, gstart, W2, W2t);
    k_gat_aggr<<<(NNODES + 3) / 4, 256, 0, stream>>>(cursor, esrc, Whbf, ls, ld_, h1bf);

    // Layer 2
    k_gemm_mfma2<<<GG, 512, 0, stream>>>(h1bf, W2t, Whbf, ls, ld_, a2s, a2d, NNODES);
    k_gat_aggr<<<(NNODES + 3) / 4, 256, 0, stream>>>(cursor, esrc, Whbf, ls, ld_, h2bf);

    // Pool + head (fused)
    k_pool_final<<<NGRAPH, 1024, 0, stream>>>(h2bf, gstart, linW, linb, out);
}

// Round 16
// 297.866 us; speedup vs baseline: 1.0280x; 1.0280x over previous
//
#include <hip/hip_runtime.h>
#include <hip/hip_bf16.h>

#define NNODES 50000
#define NEDGES 800000
#define FIN    128
#define HID    64
#define HEADS  4
#define NGRAPH 256
#define NCLS   10
#define DTOT   256   // HEADS*HID
#define ALPHA  0.01f
#define CAPLG  6          // 64 slots/node bin; Poisson(16) => P(deg>64) ~ 1e-20
#define CAP    (1 << CAPLG)

typedef short bf16x8 __attribute__((ext_vector_type(8)));
typedef float f32x4  __attribute__((ext_vector_type(4)));

#define GG     ((NNODES + 127) / 128)       // 391 gemm blocks
#define ECH    ((NEDGES + 2047) / 2048)     // 391 edge chunks (2048 edges each)
#define W1BF   (FIN * DTOT / 512)           // 64 w1t blocks (512 thr)
#define NBF    ((NNODES + 511) / 512)       // 98 gstart blocks
#define W2BF   (DTOT * DTOT / 512)          // 128 W2-transpose blocks

__device__ __forceinline__ ushort f2bf(float v) {
    return __bfloat16_as_ushort(__float2bfloat16(v));
}
__device__ __forceinline__ float blo(unsigned u) { return __uint_as_float(u << 16); }
__device__ __forceinline__ float bhi(unsigned u) { return __uint_as_float(u & 0xffff0000u); }
__device__ __forceinline__ unsigned pack2(float lo, float hi) {
    return ((unsigned)f2bf(hi) << 16) | (unsigned)f2bf(lo);
}
__device__ __forceinline__ bf16x8 cvt8(float4 lo, float4 hi) {
    bf16x8 r;
    r[0] = (short)f2bf(lo.x); r[1] = (short)f2bf(lo.y);
    r[2] = (short)f2bf(lo.z); r[3] = (short)f2bf(lo.w);
    r[4] = (short)f2bf(hi.x); r[5] = (short)f2bf(hi.y);
    r[6] = (short)f2bf(hi.z); r[7] = (short)f2bf(hi.w);
    return r;
}

// ---------------- XCD-partitioned edge binning + W1 transpose (fused; saves a launch) ----------------
// Partition p(d)=(d>>4)&7 keeps each 64B cursor/bin line on one XCD (R13-proven).
// R16: 4 CONTIGUOUS edges per thread via one uint4 dst load (wave reads 1KB linear)
// instead of 4 serial stride-512 loads — shortens the per-thread latency chain and
// makes the 4 match/atomic/store sequences independent (4x MLP). NO nt hints: each
// chunk's dst range is read by 8 partition-blocks, so cache sharing matters (R15
// regression: nt bypassed L2 and multiplied HBM fetches).
__global__ __launch_bounds__(512) void k_bin(const int* __restrict__ src,
                                             const int* __restrict__ dst,
                                             int* __restrict__ cursor,
                                             ushort* __restrict__ esrc,
                                             const float* __restrict__ W1,
                                             ushort* __restrict__ W1t) {
    if (blockIdx.x >= ECH * 8) {
        int id = (blockIdx.x - ECH * 8) * 512 + threadIdx.x;   // < 32768
        int n = id & 255, k = id >> 8;                          // k < 128
        W1t[n * FIN + (((k >> 3) ^ (n & 7)) << 3) + (k & 7)] = f2bf(W1[k * DTOT + n]);
        return;
    }
    const int p = blockIdx.x & 7;
    const int c = blockIdx.x >> 3;
    const int e4 = c * 2048 + threadIdx.x * 4;   // 4 contiguous edges per thread
    if (e4 + 3 < NEDGES) {
        int4 d4 = *(const int4*)(dst + e4);
        int dv[4] = {d4.x, d4.y, d4.z, d4.w};
#pragma unroll
        for (int k = 0; k < 4; ++k) {
            int d = dv[k];
            if (((d >> 4) & 7) == p) {
                int pos = atomicAdd(&cursor[d], 1);
                if (pos < CAP) esrc[(d << CAPLG) + pos] = (ushort)src[e4 + k];
            }
        }
    } else {
#pragma unroll
        for (int k = 0; k < 4; ++k) {
            int e = e4 + k;
            if (e < NEDGES) {
                int d = dst[e];
                if (((d >> 4) & 7) == p) {
                    int pos = atomicAdd(&cursor[d], 1);
                    if (pos < CAP) esrc[(d << CAPLG) + pos] = (ushort)src[e];
                }
            }
        }
    }
}

// ---------------- fused: gemm1 (A=f32 x) + gstart + W2 transpose ----------------
__global__ __launch_bounds__(512) void k_gemm1_fused(const float* __restrict__ x,
                                                     const ushort* __restrict__ W1t,
                                                     ushort* __restrict__ Cbf,
                                                     float* __restrict__ ls,
                                                     float* __restrict__ ld_,
                                                     const float* __restrict__ a_src,
                                                     const float* __restrict__ a_dst,
                                                     const int* __restrict__ batch,
                                                     int* __restrict__ gstart,
                                                     const float* __restrict__ W2,
                                                     ushort* __restrict__ W2t) {
    __shared__ ushort Bl[256 * 64];   // 32 KB
    const int b = blockIdx.x;
    const int tid = threadIdx.x;
    if (b >= GG) {
        const int r = b - GG;
        if (r < NBF) {
            int i = r * 512 + tid;
            if (i < NNODES) {
                int bb = batch[i];
                if (i == 0) {
                    for (int g = 0; g <= bb; ++g) gstart[g] = 0;
                } else {
                    int pb = batch[i - 1];
                    if (pb != bb) for (int g = pb + 1; g <= bb; ++g) gstart[g] = i;
                }
                if (i == NNODES - 1)
                    for (int g = bb + 1; g <= NGRAPH; ++g) gstart[g] = NNODES;
            }
        } else {
            int id = (r - NBF) * 512 + tid;   // < 65536
            int n = id & 255, k = id >> 8;
            W2t[n * DTOT + (((k >> 3) ^ (n & 7)) << 3) + (k & 7)] = f2bf(W2[k * DTOT + n]);
        }
        return;
    }

    // ---- gemm part: R7-proven structure, K=FIN, A=f32 inline cast ----
    constexpr int K = FIN;
    const int w    = tid >> 6;
    const int lane = tid & 63;
    const int l15  = lane & 15;
    const int quad = lane >> 4;
    const int m0 = b * 128;

    f32x4 acc[16];
#pragma unroll
    for (int nf = 0; nf < 16; ++nf) acc[nf] = (f32x4){0.f, 0.f, 0.f, 0.f};

    int rowA0 = m0 + w * 16 + l15;  if (rowA0 >= NNODES) rowA0 = NNODES - 1;
    const float* pa0f = x + (size_t)rowA0 * K + quad * 8;

#pragma unroll
    for (int kc = 0; kc < K / 64; ++kc) {
        {
#pragma unroll
            for (int idx = tid; idx < 2048; idx += 512) {
                int n = idx >> 3, c8 = (idx ^ n) & 7;
                *(uint4*)&Bl[n * 64 + c8 * 8] =
                    *(const uint4*)&W1t[(size_t)n * K + kc * 64 + c8 * 8];
            }
        }
        __syncthreads();
#pragma unroll
        for (int ks = 0; ks < 2; ++ks) {
            const float* p = pa0f + kc * 64 + ks * 32;
            float4 alo = *(const float4*)p;
            float4 ahi = *(const float4*)(p + 4);
            bf16x8 a0 = cvt8(alo, ahi);
#pragma unroll
            for (int nh = 0; nh < 4; ++nh) {
                bf16x8 bfr[4];
#pragma unroll
                for (int j = 0; j < 4; ++j) {
                    int n = (nh * 4 + j) * 16 + l15;
                    int c = (ks * 4 + quad) ^ (n & 7);
                    bfr[j] = *(const bf16x8*)&Bl[n * 64 + (c << 3)];
                }
#pragma unroll
                for (int j = 0; j < 4; ++j)
                    acc[nh * 4 + j] = __builtin_amdgcn_mfma_f32_16x16x32_bf16(a0, bfr[j], acc[nh * 4 + j], 0, 0, 0);
            }
        }
        __syncthreads();
    }

    float as[16], ad[16];
#pragma unroll
    for (int nf = 0; nf < 16; ++nf) {
        int head = nf >> 2;
        as[nf] = a_src[head * HID + (nf & 3) * 16 + l15];
        ad[nf] = a_dst[head * HID + (nf & 3) * 16 + l15];
    }
#pragma unroll
    for (int reg = 0; reg < 4; ++reg) {
        int row = m0 + w * 16 + quad * 4 + reg;
        bool ok = row < NNODES;
        if (ok) {
#pragma unroll
            for (int nf = 0; nf < 16; ++nf)
                Cbf[(size_t)row * DTOT + nf * 16 + l15] = f2bf(acc[nf][reg]);
        }
        float sh[4], dh[4];
#pragma unroll
        for (int head = 0; head < 4; ++head) {
            float s = 0.f, d = 0.f;
#pragma unroll
            for (int j = 0; j < 4; ++j) {
                int nf = head * 4 + j;
                s += acc[nf][reg] * as[nf];
                d += acc[nf][reg] * ad[nf];
            }
            sh[head] = s; dh[head] = d;
        }
#pragma unroll
        for (int off = 1; off < 16; off <<= 1) {
#pragma unroll
            for (int head = 0; head < 4; ++head) {
                sh[head] += __shfl_xor(sh[head], off);
                dh[head] += __shfl_xor(dh[head], off);
            }
        }
        if (ok && l15 == 0) {
#pragma unroll
            for (int head = 0; head < 4; ++head) {
                ls[row * HEADS + head]  = sh[head];
                ld_[row * HEADS + head] = dh[head];
            }
        }
    }
}

// ---------------- MFMA GEMM (layer 2): Cbf[M,256] = A[M,256] @ W2[256,256] ----------------
__global__ __launch_bounds__(512) void k_gemm_mfma2(const ushort* __restrict__ Abf,
                                                    const ushort* __restrict__ Bt,
                                                    ushort* __restrict__ Cbf,
                                                    float* __restrict__ ls,
                                                    float* __restrict__ ld_,
                                                    const float* __restrict__ a_src,
                                                    const float* __restrict__ a_dst,
                                                    int M) {
    constexpr int K = DTOT;
    __shared__ ushort Bl[256 * 64];   // 32 KB
    const int tid  = threadIdx.x;
    const int w    = tid >> 6;
    const int lane = tid & 63;
    const int l15  = lane & 15;
    const int quad = lane >> 4;
    const int m0 = blockIdx.x * 128;

    f32x4 acc[16];
#pragma unroll
    for (int nf = 0; nf < 16; ++nf) acc[nf] = (f32x4){0.f, 0.f, 0.f, 0.f};

    int rowA0 = m0 + w * 16 + l15;  if (rowA0 >= M) rowA0 = M - 1;
    const ushort* pa0b = Abf + (size_t)rowA0 * K + quad * 8;

#pragma unroll
    for (int kc = 0; kc < K / 64; ++kc) {
        {
#pragma unroll
            for (int idx = tid; idx < 2048; idx += 512) {
                int n = idx >> 3, c8 = (idx ^ n) & 7;
                *(uint4*)&Bl[n * 64 + c8 * 8] =
                    *(const uint4*)&Bt[(size_t)n * K + kc * 64 + c8 * 8];
            }
        }
        __syncthreads();
#pragma unroll
        for (int ks = 0; ks < 2; ++ks) {
            bf16x8 a0 = *(const bf16x8*)(pa0b + kc * 64 + ks * 32);
#pragma unroll
            for (int nh = 0; nh < 4; ++nh) {
                bf16x8 bfr[4];
#pragma unroll
                for (int j = 0; j < 4; ++j) {
                    int n = (nh * 4 + j) * 16 + l15;
                    int c = (ks * 4 + quad) ^ (n & 7);
                    bfr[j] = *(const bf16x8*)&Bl[n * 64 + (c << 3)];
                }
#pragma unroll
                for (int j = 0; j < 4; ++j)
                    acc[nh * 4 + j] = __builtin_amdgcn_mfma_f32_16x16x32_bf16(a0, bfr[j], acc[nh * 4 + j], 0, 0, 0);
            }
        }
        __syncthreads();
    }

    float as[16], ad[16];
#pragma unroll
    for (int nf = 0; nf < 16; ++nf) {
        int head = nf >> 2;
        as[nf] = a_src[head * HID + (nf & 3) * 16 + l15];
        ad[nf] = a_dst[head * HID + (nf & 3) * 16 + l15];
    }
#pragma unroll
    for (int reg = 0; reg < 4; ++reg) {
        int row = m0 + w * 16 + quad * 4 + reg;
        bool ok = row < M;
        if (ok) {
#pragma unroll
            for (int nf = 0; nf < 16; ++nf)
                Cbf[(size_t)row * DTOT + nf * 16 + l15] = f2bf(acc[nf][reg]);
        }
        float sh[4], dh[4];
#pragma unroll
        for (int head = 0; head < 4; ++head) {
            float s = 0.f, d = 0.f;
#pragma unroll
            for (int j = 0; j < 4; ++j) {
                int nf = head * 4 + j;
                s += acc[nf][reg] * as[nf];
                d += acc[nf][reg] * ad[nf];
            }
            sh[head] = s; dh[head] = d;
        }
#pragma unroll
        for (int off = 1; off < 16; off <<= 1) {
#pragma unroll
            for (int head = 0; head < 4; ++head) {
                sh[head] += __shfl_xor(sh[head], off);
                dh[head] += __shfl_xor(dh[head], off);
            }
        }
        if (ok && l15 == 0) {
#pragma unroll
            for (int head = 0; head < 4; ++head) {
                ls[row * HEADS + head]  = sh[head];
                ld_[row * HEADS + head] = dh[head];
            }
        }
    }
}

// ---------------- fused softmax + gather-aggregate + ELU (R7-exact: at its memory wall) ----------------
__global__ __launch_bounds__(256) void k_gat_aggr(const int* __restrict__ cnt,
                                                  const ushort* __restrict__ esrc,
                                                  const ushort* __restrict__ Whbf,
                                                  const float* __restrict__ ls,
                                                  const float* __restrict__ ld_,
                                                  ushort* __restrict__ out) {
    const int wv   = threadIdx.x >> 6;
    const int lane = threadIdx.x & 63;
    const int i    = blockIdx.x * 4 + wv;
    if (i >= NNODES) return;
    const int half = lane >> 5;
    const int l32  = lane & 31;
    const int h    = l32 >> 3;
    const int e0 = i << CAPLG;
    int deg = cnt[i]; if (deg > CAP) deg = CAP;
    const int e1 = e0 + deg;
    const float ldv = ld_[i * HEADS + h];

    float ac[8] = {};
    float z = 0.f;
    const int ch = 8 * l32;
    int e = e0 + half;
    for (; e + 6 < e1; e += 8) {
        int s0 = (int)esrc[e], s1 = (int)esrc[e + 2], s2 = (int)esrc[e + 4], s3 = (int)esrc[e + 6];
        float l0 = ls[s0 * HEADS + h] + ldv;
        float l1 = ls[s1 * HEADS + h] + ldv;
        float l2 = ls[s2 * HEADS + h] + ldv;
        float l3 = ls[s3 * HEADS + h] + ldv;
        uint4 u0 = *(const uint4*)&Whbf[(size_t)s0 * DTOT + ch];
        uint4 u1 = *(const uint4*)&Whbf[(size_t)s1 * DTOT + ch];
        uint4 u2 = *(const uint4*)&Whbf[(size_t)s2 * DTOT + ch];
        uint4 u3 = *(const uint4*)&Whbf[(size_t)s3 * DTOT + ch];
        float p0 = __expf(l0 > 0.f ? l0 : ALPHA * l0);
        float p1 = __expf(l1 > 0.f ? l1 : ALPHA * l1);
        float p2 = __expf(l2 > 0.f ? l2 : ALPHA * l2);
        float p3 = __expf(l3 > 0.f ? l3 : ALPHA * l3);
        z += p0 + p1 + p2 + p3;
        ac[0] = fmaf(p0, blo(u0.x), ac[0]); ac[1] = fmaf(p0, bhi(u0.x), ac[1]);
        ac[2] = fmaf(p0, blo(u0.y), ac[2]); ac[3] = fmaf(p0, bhi(u0.y), ac[3]);
        ac[4] = fmaf(p0, blo(u0.z), ac[4]); ac[5] = fmaf(p0, bhi(u0.z), ac[5]);
        ac[6] = fmaf(p0, blo(u0.w), ac[6]); ac[7] = fmaf(p0, bhi(u0.w), ac[7]);
        ac[0] = fmaf(p1, blo(u1.x), ac[0]); ac[1] = fmaf(p1, bhi(u1.x), ac[1]);
        ac[2] = fmaf(p1, blo(u1.y), ac[2]); ac[3] = fmaf(p1, bhi(u1.y), ac[3]);
        ac[4] = fmaf(p1, blo(u1.z), ac[4]); ac[5] = fmaf(p1, bhi(u1.z), ac[5]);
        ac[6] = fmaf(p1, blo(u1.w), ac[6]); ac[7] = fmaf(p1, bhi(u1.w), ac[7]);
        ac[0] = fmaf(p2, blo(u2.x), ac[0]); ac[1] = fmaf(p2, bhi(u2.x), ac[1]);
        ac[2] = fmaf(p2, blo(u2.y), ac[2]); ac[3] = fmaf(p2, bhi(u2.y), ac[3]);
        ac[4] = fmaf(p2, blo(u2.z), ac[4]); ac[5] = fmaf(p2, bhi(u2.z), ac[5]);
        ac[6] = fmaf(p2, blo(u2.w), ac[6]); ac[7] = fmaf(p2, bhi(u2.w), ac[7]);
        ac[0] = fmaf(p3, blo(u3.x), ac[0]); ac[1] = fmaf(p3, bhi(u3.x), ac[1]);
        ac[2] = fmaf(p3, blo(u3.y), ac[2]); ac[3] = fmaf(p3, bhi(u3.y), ac[3]);
        ac[4] = fmaf(p3, blo(u3.z), ac[4]); ac[5] = fmaf(p3, bhi(u3.z), ac[5]);
        ac[6] = fmaf(p3, blo(u3.w), ac[6]); ac[7] = fmaf(p3, bhi(u3.w), ac[7]);
    }
    for (; e < e1; e += 2) {
        int s0 = (int)esrc[e];
        float l0 = ls[s0 * HEADS + h] + ldv;
        uint4 u0 = *(const uint4*)&Whbf[(size_t)s0 * DTOT + ch];
        float p0 = __expf(l0 > 0.f ? l0 : ALPHA * l0);
        z += p0;
        ac[0] = fmaf(p0, blo(u0.x), ac[0]); ac[1] = fmaf(p0, bhi(u0.x), ac[1]);
        ac[2] = fmaf(p0, blo(u0.y), ac[2]); ac[3] = fmaf(p0, bhi(u0.y), ac[3]);
        ac[4] = fmaf(p0, blo(u0.z), ac[4]); ac[5] = fmaf(p0, bhi(u0.z), ac[5]);
        ac[6] = fmaf(p0, blo(u0.w), ac[6]); ac[7] = fmaf(p0, bhi(u0.w), ac[7]);
    }

#pragma unroll
    for (int j = 0; j < 8; ++j) ac[j] += __shfl_xor(ac[j], 32);
    z += __shfl_xor(z, 32);

    if (half == 0) {
        const float inv = 1.f / (z + 1e-16f);
        float v[8];
#pragma unroll
        for (int j = 0; j < 8; ++j) {
            float t = ac[j] * inv;
            v[j] = t > 0.f ? t : __expf(t) - 1.f;
        }
        uint4 pk;
        pk.x = pack2(v[0], v[1]);
        pk.y = pack2(v[2], v[3]);
        pk.z = pack2(v[4], v[5]);
        pk.w = pack2(v[6], v[7]);
        *(uint4*)(out + (size_t)i * DTOT + ch) = pk;
    }
}

// ---------------- fused pooling + final linear (vectorized; 34KB LDS) ----------------
__global__ __launch_bounds__(1024) void k_pool_final(const ushort* __restrict__ h2bf,
                                                     const int* __restrict__ gstart,
                                                     const float* __restrict__ W,
                                                     const float* __restrict__ b,
                                                     float* __restrict__ out) {
    __shared__ float smx[16][256];   // 16 KB
    __shared__ float ssm[16][256];   // 16 KB
    __shared__ float pooled[2 * DTOT];
    int g = blockIdx.x, t = threadIdx.x;
    int cg = t & 31, j = t >> 5;          // 32 node-strides, 8 channels/thread
    int s = gstart[g], e = gstart[g + 1];
    float mx[8], sm[8];
#pragma unroll
    for (int k = 0; k < 8; ++k) { mx[k] = -INFINITY; sm[k] = 0.f; }
    for (int n = s + j; n < e; n += 32) {
        uint4 u = *(const uint4*)&h2bf[(size_t)n * DTOT + cg * 8];
        float v0 = blo(u.x), v1 = bhi(u.x), v2 = blo(u.y), v3 = bhi(u.y);
        float v4 = blo(u.z), v5 = bhi(u.z), v6 = blo(u.w), v7 = bhi(u.w);
        mx[0] = fmaxf(mx[0], v0); sm[0] += v0;
        mx[1] = fmaxf(mx[1], v1); sm[1] += v1;
        mx[2] = fmaxf(mx[2], v2); sm[2] += v2;
        mx[3] = fmaxf(mx[3], v3); sm[3] += v3;
        mx[4] = fmaxf(mx[4], v4); sm[4] += v4;
        mx[5] = fmaxf(mx[5], v5); sm[5] += v5;
        mx[6] = fmaxf(mx[6], v6); sm[6] += v6;
        mx[7] = fmaxf(mx[7], v7); sm[7] += v7;
    }
#pragma unroll
    for (int k = 0; k < 8; ++k) {
        mx[k] = fmaxf(mx[k], __shfl_xor(mx[k], 32));
        sm[k] += __shfl_xor(sm[k], 32);
    }
    int wave = t >> 6, lane = t & 63;
    if (lane < 32) {
        *(float4*)&smx[wave][lane * 8]     = make_float4(mx[0], mx[1], mx[2], mx[3]);
        *(float4*)&smx[wave][lane * 8 + 4] = make_float4(mx[4], mx[5], mx[6], mx[7]);
        *(float4*)&ssm[wave][lane * 8]     = make_float4(sm[0], sm[1], sm[2], sm[3]);
        *(float4*)&ssm[wave][lane * 8 + 4] = make_float4(sm[4], sm[5], sm[6], sm[7]);
    }
    __syncthreads();
    if (t < 256) {
        float m = -INFINITY, su = 0.f;
#pragma unroll
        for (int jj = 0; jj < 16; ++jj) {
            m = fmaxf(m, smx[jj][t]);
            su += ssm[jj][t];
        }
        int cnt = e - s;
        if (cnt <= 0) m = 0.f;
        pooled[t] = m;
        pooled[DTOT + t] = su / (float)(cnt > 0 ? cnt : 1);
    }
    __syncthreads();
    int wv = t >> 6;
    if (wv < NCLS) {
        float acc = 0.f;
        for (int k = lane; k < 2 * DTOT; k += 64)
            acc += pooled[k] * W[k * NCLS + wv];
#pragma unroll
        for (int off = 32; off; off >>= 1) acc += __shfl_down(acc, off);
        if (lane == 0)
            out[g * NCLS + wv] = acc + b[wv];
    }
}

extern "C" void kernel_launch(void* const* d_in, const int* in_sizes, int n_in,
                              void* d_out, int out_size, void* d_ws, size_t ws_size,
                              hipStream_t stream) {
    const float* x     = (const float*)d_in[0];
    const int*   ei    = (const int*)d_in[1];
    const int*   batch = (const int*)d_in[2];
    const float* W1    = (const float*)d_in[3];
    const float* a1s   = (const float*)d_in[4];
    const float* a1d   = (const float*)d_in[5];
    const float* W2    = (const float*)d_in[6];
    const float* a2s   = (const float*)d_in[7];
    const float* a2d   = (const float*)d_in[8];
    const float* linW  = (const float*)d_in[9];
    const float* linb  = (const float*)d_in[10];
    float* out = (float*)d_out;

    const int* src = ei;
    const int* dst = ei + NEDGES;

    size_t off = 0;
    char* base = (char*)d_ws;
    auto alloc = [&](size_t bytes) -> void* {
        void* p = base + off;
        off += (bytes + 255) & ~(size_t)255;
        return p;
    };
    ushort* Whbf   = (ushort*)alloc((size_t)NNODES * DTOT * 2);
    ushort* h1bf   = (ushort*)alloc((size_t)NNODES * DTOT * 2);
    ushort* h2bf   = (ushort*)alloc((size_t)NNODES * DTOT * 2);
    float*  ls     = (float*)alloc((size_t)NNODES * HEADS * 4);
    float*  ld_    = (float*)alloc((size_t)NNODES * HEADS * 4);
    int*    cursor = (int*)alloc((size_t)NNODES * 4);
    ushort* esrc   = (ushort*)alloc((size_t)(NNODES << CAPLG) * 2);  // 6.4 MB bins
    int*    gstart = (int*)alloc((size_t)(NGRAPH + 1) * 4);
    ushort* W1t    = (ushort*)alloc((size_t)DTOT * FIN * 2);
    ushort* W2t    = (ushort*)alloc((size_t)DTOT * DTOT * 2);

    hipMemsetAsync(cursor, 0, (size_t)NNODES * 4, stream);

    // Partitioned binning (uint4 contiguous dst loads; L2-resident bins) + W1t tail
    k_bin<<<ECH * 8 + W1BF, 512, 0, stream>>>(src, dst, cursor, esrc, W1, W1t);

    // Layer 1 GEMM fused with gstart | W2 transpose (tiny tails)
    int fgrid = GG + NBF + W2BF;   // 391 + 98 + 128 = 617
    k_gemm1_fused<<<fgrid, 512, 0, stream>>>(x, W1t, Whbf, ls, ld_, a1s, a1d,
                                             batch, gstart, W2, W2t);
    k_gat_aggr<<<(NNODES + 3) / 4, 256, 0, stream>>>(cursor, esrc, Whbf, ls, ld_, h1bf);

    // Layer 2
    k_gemm_mfma2<<<GG, 512, 0, stream>>>(h1bf, W2t, Whbf, ls, ld_, a2s, a2d, NNODES);
    k_gat_aggr<<<(NNODES + 3) / 4, 256, 0, stream>>>(cursor, esrc, Whbf, ls, ld_, h2bf);

    // Pool + head (fused)
    k_pool_final<<<NGRAPH, 1024, 0, stream>>>(h2bf, gstart, linW, linb, out);
}